// Round 1
// baseline (76.505 us; speedup 1.0000x reference)
//
#include <hip/hip_runtime.h>
#include <hip/hip_bf16.h>

// RMSNorm over last dim D=2048, rows = B*S = 16384, fp32 in/out.
// out[r][d] = x[r][d] * rsqrt(mean(x[r]^2) + 5e-6) * gamma[r][d]
//
// One 256-thread block per row. Each thread owns 8 floats (2x float4,
// stride-256 float4 pattern -> consecutive lanes hit consecutive 16B
// segments = fully coalesced). Single pass: x stays in registers across
// the reduction, gamma loaded after the rsqrt.

#define D_DIM 2048
#define VEC_PER_ROW (D_DIM / 4)   // 512 float4 per row
#define EPS 5e-6f

__global__ __launch_bounds__(256) void rmsnorm_f32_kernel(
    const float4* __restrict__ x,
    const float4* __restrict__ g,
    float4* __restrict__ out)
{
    const int t = threadIdx.x;
    const long base = (long)blockIdx.x * VEC_PER_ROW;

    // Load this thread's 8 elements (2 float4, coalesced), accumulate squares.
    float4 xv0 = x[base + t];
    float4 xv1 = x[base + t + 256];
    float ss = xv0.x * xv0.x + xv0.y * xv0.y + xv0.z * xv0.z + xv0.w * xv0.w
             + xv1.x * xv1.x + xv1.y * xv1.y + xv1.z * xv1.z + xv1.w * xv1.w;

    // Wave-64 butterfly-free down reduction.
    #pragma unroll
    for (int off = 32; off > 0; off >>= 1)
        ss += __shfl_down(ss, off, 64);

    // Cross-wave (4 waves) reduction via tiny LDS scratch.
    __shared__ float wsum[4];
    const int wave = t >> 6;
    if ((t & 63) == 0) wsum[wave] = ss;
    __syncthreads();

    const float total = wsum[0] + wsum[1] + wsum[2] + wsum[3];
    const float inv = rsqrtf(total * (1.0f / (float)D_DIM) + EPS);

    // Apply: x * inv * gamma, write back (coalesced float4 stores).
    float4 gv0 = g[base + t];
    float4 gv1 = g[base + t + 256];
    float4 o0, o1;
    o0.x = xv0.x * inv * gv0.x;
    o0.y = xv0.y * inv * gv0.y;
    o0.z = xv0.z * inv * gv0.z;
    o0.w = xv0.w * inv * gv0.w;
    o1.x = xv1.x * inv * gv1.x;
    o1.y = xv1.y * inv * gv1.y;
    o1.z = xv1.z * inv * gv1.z;
    o1.w = xv1.w * inv * gv1.w;
    out[base + t] = o0;
    out[base + t + 256] = o1;
}

extern "C" void kernel_launch(void* const* d_in, const int* in_sizes, int n_in,
                              void* d_out, int out_size, void* d_ws, size_t ws_size,
                              hipStream_t stream) {
    const float* x = (const float*)d_in[0];
    const float* g = (const float*)d_in[1];
    float* out = (float*)d_out;

    const int rows = out_size / D_DIM;  // 4*4096 = 16384
    rmsnorm_f32_kernel<<<rows, 256, 0, stream>>>(
        (const float4*)x, (const float4*)g, (float4*)out);
}

// Round 2
// 59.598 us; speedup vs baseline: 1.2837x; 1.2837x over previous
//
#include <hip/hip_runtime.h>
#include <hip/hip_bf16.h>

// RMSNorm over last dim D=2048, rows = B*S = 16384, fp32 in/out.
// out[r][d] = x[r][d] * rsqrt(mean(x[r]^2) + 5e-6) * gamma[r][d]
//
// R2 changes vs R1:
//  - gamma loads issued UP FRONT with x loads (overlap the two memory
//    phases instead of serializing gamma-load after the reduction barrier)
//  - non-temporal stores for the output (write stream never re-read;
//    keeps the 268 MB read set resident in the 256 MB L3 across replays)

#define D_DIM 2048
#define VEC_PER_ROW (D_DIM / 4)   // 512 float4 per row
#define EPS 5e-6f

typedef float f32x4 __attribute__((ext_vector_type(4)));

__global__ __launch_bounds__(256) void rmsnorm_f32_kernel(
    const float4* __restrict__ x,
    const float4* __restrict__ g,
    float4* __restrict__ out)
{
    const int t = threadIdx.x;
    const long base = (long)blockIdx.x * VEC_PER_ROW;

    // Issue ALL loads first (x and gamma) so both memory phases overlap.
    float4 xv0 = x[base + t];
    float4 xv1 = x[base + t + 256];
    float4 gv0 = g[base + t];
    float4 gv1 = g[base + t + 256];

    float ss = xv0.x * xv0.x + xv0.y * xv0.y + xv0.z * xv0.z + xv0.w * xv0.w
             + xv1.x * xv1.x + xv1.y * xv1.y + xv1.z * xv1.z + xv1.w * xv1.w;

    // Wave-64 down-shuffle reduction.
    #pragma unroll
    for (int off = 32; off > 0; off >>= 1)
        ss += __shfl_down(ss, off, 64);

    // Cross-wave (4 waves) reduction via tiny LDS scratch.
    __shared__ float wsum[4];
    const int wave = t >> 6;
    if ((t & 63) == 0) wsum[wave] = ss;
    __syncthreads();

    const float total = wsum[0] + wsum[1] + wsum[2] + wsum[3];
    const float inv = rsqrtf(total * (1.0f / (float)D_DIM) + EPS);

    float4 o0, o1;
    o0.x = xv0.x * inv * gv0.x;
    o0.y = xv0.y * inv * gv0.y;
    o0.z = xv0.z * inv * gv0.z;
    o0.w = xv0.w * inv * gv0.w;
    o1.x = xv1.x * inv * gv1.x;
    o1.y = xv1.y * inv * gv1.y;
    o1.z = xv1.z * inv * gv1.z;
    o1.w = xv1.w * inv * gv1.w;

    // Non-temporal stores: bypass L2/L3 so the write stream doesn't evict
    // the input read set from Infinity Cache.
    __builtin_nontemporal_store(*(const f32x4*)&o0, (f32x4*)&out[base + t]);
    __builtin_nontemporal_store(*(const f32x4*)&o1, (f32x4*)&out[base + t + 256]);
}

extern "C" void kernel_launch(void* const* d_in, const int* in_sizes, int n_in,
                              void* d_out, int out_size, void* d_ws, size_t ws_size,
                              hipStream_t stream) {
    const float* x = (const float*)d_in[0];
    const float* g = (const float*)d_in[1];
    float* out = (float*)d_out;

    const int rows = out_size / D_DIM;  // 4*4096 = 16384
    rmsnorm_f32_kernel<<<rows, 256, 0, stream>>>(
        (const float4*)x, (const float4*)g, (float4*)out);
}